// Round 2
// baseline (705.194 us; speedup 1.0000x reference)
//
#include <hip/hip_runtime.h>
#include <hip/hip_bf16.h>

// SGDW update: out = p * (1 - LR*WD) - LR * (MOM*v + g)
// LR=0.01, MOM=0.9, WD=0.0001, NESTEROV=false
//
// Inputs (fp32), dict order from setup_inputs():
//   d_in[3*i+0] = p_i, d_in[3*i+1] = g_i, d_in[3*i+2] = v_i   for i in 0..3
// Output: 4 updated param tensors concatenated flat (fp32).
// Memory-bound: ~974 MB traffic/call -> ~155 us floor at 6.3 TB/s.
// Single fused launch over all 4 tensors (segment via prefix-sum compares;
// tensor 0 is 84% of elements so waves are almost always uniform).

#define SGDW_LR 0.01f
#define SGDW_MOM 0.9f

__global__ __launch_bounds__(256) void sgdw_fused_v4(
    const float4* __restrict__ p0, const float4* __restrict__ g0, const float4* __restrict__ v0,
    const float4* __restrict__ p1, const float4* __restrict__ g1, const float4* __restrict__ v1,
    const float4* __restrict__ p2, const float4* __restrict__ g2, const float4* __restrict__ v2,
    const float4* __restrict__ p3, const float4* __restrict__ g3, const float4* __restrict__ v3,
    float4* __restrict__ out,
    int c1, int c2, int c3, int total4)   // prefix sums in float4 units
{
    const float scale = 1.0f - SGDW_LR * 0.0001f; // 1 - lr*wd
    int i = blockIdx.x * blockDim.x + threadIdx.x;
    const int stride = gridDim.x * blockDim.x;
    for (; i < total4; i += stride) {
        const float4* __restrict__ p;
        const float4* __restrict__ g;
        const float4* __restrict__ v;
        int j;
        if (i < c1)      { p = p0; g = g0; v = v0; j = i; }
        else if (i < c2) { p = p1; g = g1; v = v1; j = i - c1; }
        else if (i < c3) { p = p2; g = g2; v = v2; j = i - c2; }
        else             { p = p3; g = g3; v = v3; j = i - c3; }
        float4 P = p[j];
        float4 G = g[j];
        float4 V = v[j];
        float4 o;
        // vel = MOM*v + g ; out = p*scale - LR*vel
        o.x = fmaf(P.x, scale, -SGDW_LR * fmaf(SGDW_MOM, V.x, G.x));
        o.y = fmaf(P.y, scale, -SGDW_LR * fmaf(SGDW_MOM, V.y, G.y));
        o.z = fmaf(P.z, scale, -SGDW_LR * fmaf(SGDW_MOM, V.z, G.z));
        o.w = fmaf(P.w, scale, -SGDW_LR * fmaf(SGDW_MOM, V.w, G.w));
        out[i] = o;
    }
}

extern "C" void kernel_launch(void* const* d_in, const int* in_sizes, int n_in,
                              void* d_out, int out_size, void* d_ws, size_t ws_size,
                              hipStream_t stream)
{
    (void)d_ws; (void)ws_size; (void)out_size; (void)n_in;

    // Prefix sums in float4 units (all sizes are multiples of 4).
    const int n0 = in_sizes[0] >> 2;
    const int n1 = in_sizes[3] >> 2;
    const int n2 = in_sizes[6] >> 2;
    const int n3 = in_sizes[9] >> 2;
    const int c1 = n0;
    const int c2 = c1 + n1;
    const int c3 = c2 + n2;
    const int total4 = c3 + n3;

    const int block = 256;
    int blocks = (total4 + block - 1) / block;
    if (blocks > 2048) blocks = 2048; // 256 CU * 8 blocks/CU, grid-stride the rest

    sgdw_fused_v4<<<blocks, block, 0, stream>>>(
        (const float4*)d_in[0],  (const float4*)d_in[1],  (const float4*)d_in[2],
        (const float4*)d_in[3],  (const float4*)d_in[4],  (const float4*)d_in[5],
        (const float4*)d_in[6],  (const float4*)d_in[7],  (const float4*)d_in[8],
        (const float4*)d_in[9],  (const float4*)d_in[10], (const float4*)d_in[11],
        (float4*)d_out, c1, c2, c3, total4);
}